// Round 2
// baseline (97.822 us; speedup 1.0000x reference)
//
#include <hip/hip_runtime.h>
#include <hip/hip_bf16.h>

// Problem constants (from reference)
#define B_    64
#define T_    500
#define DIN   1024
#define DOUT  128
#define EPSV  1e-8f
#define BM    32          // t-rows per workgroup tile
#define NTILE 16          // ceil(500/32)

typedef __attribute__((ext_vector_type(8))) short bf16x8;  // MFMA A/B frag (8 bf16)
typedef __attribute__((ext_vector_type(4))) float f32x4;   // MFMA C/D frag

// Workspace layout (byte offsets; total ~1.02 MB)
//   wT    : bf16 [DOUT][DIN]          @ 0        (262144 B)  w transposed + bf16
//   wtab  : f32  [T_][DOUT]           @ 262144   (256000 B)  c[t][d] = 1 - beta[d]^(T-t)
//   scale : f32  [DOUT]               @ 518144   (512 B)     1/(T*(norm+eps))
//   part  : f32  [B_][NTILE][DOUT]    @ 518656   (524288 B)  per-tile weighted partial sums
#define OFF_WTAB  262144
#define OFF_SCALE 518144
#define OFF_PART  518656

__device__ inline short f2bf(float f) {
    __hip_bfloat16 h = __float2bfloat16(f);
    return __builtin_bit_cast(short, h);
}

// ---------------- prep: transpose/convert w, norm->scale, weight table ----------------
__global__ __launch_bounds__(256) void prep_kernel(
    const float* __restrict__ w, const float* __restrict__ beta,
    __hip_bfloat16* __restrict__ wT, float* __restrict__ wtab,
    float* __restrict__ scale)
{
    int bid = blockIdx.x, tid = threadIdx.x;
    if (bid < 512) {
        // 512*256 = 131072 = DOUT*DIN : wT[d][k] = bf16(w[k][d])
        int i = bid * 256 + tid;
        int d = i >> 10, k = i & 1023;
        wT[(size_t)d * DIN + k] = __float2bfloat16(w[(size_t)k * DOUT + d]);
    } else if (bid < 640) {
        // one block per output column d: norm = sum_c w[c][d]^2
        int d = bid - 512;
        __shared__ float red[256];
        float s = 0.f;
        for (int c = tid; c < DIN; c += 256) {
            float v = w[(size_t)c * DOUT + d];
            s += v * v;
        }
        red[tid] = s;
        __syncthreads();
        for (int off = 128; off > 0; off >>= 1) {
            if (tid < off) red[tid] += red[tid + off];
            __syncthreads();
        }
        if (tid == 0) scale[d] = 1.f / ((red[0] + EPSV) * (float)T_);
    } else {
        // 250*256 >= 64000 = T_*DOUT : wtab[t][d] = 1 - beta[d]^(T-t)
        int i = (bid - 640) * 256 + tid;
        if (i < T_ * DOUT) {
            int t = i >> 7, d = i & 127;
            wtab[i] = 1.f - powf(beta[d], (float)(T_ - t));
        }
    }
}

// ---------------- main: fused GEMM + weighted time-reduction ----------------
// grid: 64 batches x 16 t-tiles. Block = 256 = 4 waves; wave `w` owns cols
// [w*32, w*32+32) x all 32 rows of the tile. MFMA 16x16x32 bf16, fp32 acc.
// A frag: lane reads x[t0 + rf*16 + (lane&15)][k0 + (lane>>4)*8 + 0..7] (fp32->bf16)
// B frag: lane reads wT[c0 + cf*16 + (lane&15)][k0 + (lane>>4)*8 + 0..7]
// C frag: col = lane&15, row = (lane>>4)*4 + reg   [verified gfx950 mapping]
__global__ __launch_bounds__(256) void gemm_kernel(
    const float* __restrict__ x, const __hip_bfloat16* __restrict__ wT,
    const float* __restrict__ wtab, float* __restrict__ partials)
{
    int wg   = blockIdx.x;
    int b    = wg >> 4;
    int tile = wg & 15;
    int t0   = tile * BM;
    int wave = threadIdx.x >> 6;
    int lane = threadIdx.x & 63;
    int arow = lane & 15;
    int kblk = lane >> 4;

    const float* xb = x + (size_t)b * T_ * DIN;

    // row addresses (clamp t>=500; their weight will be 0 so garbage*0 = 0, values finite)
    int tr0 = t0 + arow;       int tc0 = tr0 < T_ ? tr0 : T_ - 1;
    int tr1 = t0 + 16 + arow;  int tc1 = tr1 < T_ ? tr1 : T_ - 1;

    const float* pa0 = xb + (size_t)tc0 * DIN + kblk * 8;
    const float* pa1 = xb + (size_t)tc1 * DIN + kblk * 8;

    int c0 = wave * 32;
    const __hip_bfloat16* pb0 = wT + (size_t)(c0 + arow) * DIN + kblk * 8;
    const __hip_bfloat16* pb1 = wT + (size_t)(c0 + 16 + arow) * DIN + kblk * 8;

    f32x4 acc00 = {0.f,0.f,0.f,0.f}, acc01 = {0.f,0.f,0.f,0.f};
    f32x4 acc10 = {0.f,0.f,0.f,0.f}, acc11 = {0.f,0.f,0.f,0.f};

    for (int k0 = 0; k0 < DIN; k0 += 32) {
        float4 a0l = *reinterpret_cast<const float4*>(pa0 + k0);
        float4 a0h = *reinterpret_cast<const float4*>(pa0 + k0 + 4);
        float4 a1l = *reinterpret_cast<const float4*>(pa1 + k0);
        float4 a1h = *reinterpret_cast<const float4*>(pa1 + k0 + 4);
        bf16x8 bf0 = *reinterpret_cast<const bf16x8*>(pb0 + k0);
        bf16x8 bf1 = *reinterpret_cast<const bf16x8*>(pb1 + k0);

        bf16x8 af0, af1;
        af0[0] = f2bf(a0l.x); af0[1] = f2bf(a0l.y); af0[2] = f2bf(a0l.z); af0[3] = f2bf(a0l.w);
        af0[4] = f2bf(a0h.x); af0[5] = f2bf(a0h.y); af0[6] = f2bf(a0h.z); af0[7] = f2bf(a0h.w);
        af1[0] = f2bf(a1l.x); af1[1] = f2bf(a1l.y); af1[2] = f2bf(a1l.z); af1[3] = f2bf(a1l.w);
        af1[4] = f2bf(a1h.x); af1[5] = f2bf(a1h.y); af1[6] = f2bf(a1h.z); af1[7] = f2bf(a1h.w);

        acc00 = __builtin_amdgcn_mfma_f32_16x16x32_bf16(af0, bf0, acc00, 0, 0, 0);
        acc01 = __builtin_amdgcn_mfma_f32_16x16x32_bf16(af0, bf1, acc01, 0, 0, 0);
        acc10 = __builtin_amdgcn_mfma_f32_16x16x32_bf16(af1, bf0, acc10, 0, 0, 0);
        acc11 = __builtin_amdgcn_mfma_f32_16x16x32_bf16(af1, bf1, acc11, 0, 0, 0);
    }

    // Epilogue: out_part[d] = sum over the 32 tile rows of c[t][d] * h[t][d].
    // Lane holds rows rf*16 + kblk*4 + r (r=0..3), col c0 + cf*16 + arow.
    int d0 = c0 + arow;
    int d1 = c0 + 16 + arow;
    float s0 = 0.f, s1 = 0.f;
#pragma unroll
    for (int r = 0; r < 4; ++r) {
        int ta = t0 + kblk * 4 + r;   // rf = 0
        int tb = ta + 16;             // rf = 1
        float wa0 = (ta < T_) ? wtab[ta * DOUT + d0] : 0.f;
        float wb0 = (tb < T_) ? wtab[tb * DOUT + d0] : 0.f;
        float wa1 = (ta < T_) ? wtab[ta * DOUT + d1] : 0.f;
        float wb1 = (tb < T_) ? wtab[tb * DOUT + d1] : 0.f;
        s0 += wa0 * acc00[r] + wb0 * acc10[r];
        s1 += wa1 * acc01[r] + wb1 * acc11[r];
    }
    // reduce over the 4 lane-groups (lane bits 4-5 = kblk) that hold the 16 rows
    s0 += __shfl_xor(s0, 16); s0 += __shfl_xor(s0, 32);
    s1 += __shfl_xor(s1, 16); s1 += __shfl_xor(s1, 32);

    if (kblk == 0) {
        float* p = partials + ((size_t)b * NTILE + tile) * DOUT;
        p[d0] = s0;
        p[d1] = s1;
    }
}

// ---------------- finalize: sum partials, scale, bias ----------------
__global__ __launch_bounds__(256) void finalize_kernel(
    const float* __restrict__ partials, const float* __restrict__ scale,
    const float* __restrict__ bias, float* __restrict__ out)
{
    int i = blockIdx.x * 256 + threadIdx.x;  // 8192 = B_*DOUT
    int b = i >> 7, d = i & 127;
    float s = 0.f;
#pragma unroll
    for (int tile = 0; tile < NTILE; ++tile)
        s += partials[((size_t)b * NTILE + tile) * DOUT + d];
    out[i] = s * scale[d] - bias[d];
}

extern "C" void kernel_launch(void* const* d_in, const int* in_sizes, int n_in,
                              void* d_out, int out_size, void* d_ws, size_t ws_size,
                              hipStream_t stream) {
    const float* x    = (const float*)d_in[0];  // [64][500][1024]
    const float* w    = (const float*)d_in[1];  // [1024][128]
    const float* beta = (const float*)d_in[2];  // [128]
    const float* bias = (const float*)d_in[3];  // [128]
    float* out = (float*)d_out;                 // [64][128] fp32

    char* ws = (char*)d_ws;
    __hip_bfloat16* wT = (__hip_bfloat16*)(ws);
    float* wtab     = (float*)(ws + OFF_WTAB);
    float* scale    = (float*)(ws + OFF_SCALE);
    float* partials = (float*)(ws + OFF_PART);

    prep_kernel<<<890, 256, 0, stream>>>(w, beta, wT, wtab, scale);
    gemm_kernel<<<B_ * NTILE, 256, 0, stream>>>(x, wT, wtab, partials);
    finalize_kernel<<<(B_ * DOUT) / 256, 256, 0, stream>>>(partials, scale, bias, out);
}